// Round 6
// baseline (46.288 us; speedup 1.0000x reference)
//
#include <hip/hip_runtime.h>

// SSIM loss, N=64 images, 1 ch, 384x384 f32, 7x7 box, VALID -> 378x378. out = -mean(S).
//
// R6: register-resident band walker, occupancy-oriented rework of R5.
//  - R5 was grid-capped at 1.69 waves/SIMD (1728 one-wave blocks / 1024 SIMDs):
//    latency-bound. R6: RB 14 -> 7 (3456 blocks = 3.38 waves/SIMD) and the
//    7-deep raw-row register history (84 VGPR) is replaced by RE-LOADING the
//    old row from cache (loaded ~7 steps earlier; L1/L2 hit, prefetched one
//    full step ahead). VGPR budget ~120 -> 4 waves/SIMD allowed.
//  - Lane l owns cols 6l..6l+5 (64*6 = 384: full width, no clamping).
//  - Vertical {x,y,xx,yy,xy} sums slide in registers: add prefetched new row,
//    subtract re-loaded old row.
//  - Horizontal 7-tap: local sliding sum + 6 independent depth-1 shuffles/moment.
//  - Two-kernel deterministic reduction (R3 showed fused atomic tail = 6x loss).

constexpr int IND   = 384;
constexpr int OUTD  = 378;
constexpr int RB    = 7;             // output rows per band
constexpr int BANDS = OUTD / RB;     // 54
constexpr int CPL   = 6;             // cols per lane

using f32x2 = __attribute__((ext_vector_type(2))) float;

__global__ __launch_bounds__(64, 4)
void ssim_band(const float* __restrict__ X, const float* __restrict__ Y,
               const float* __restrict__ MX, float* __restrict__ blocksum)
{
    const int band = blockIdx.x;
    const int n    = blockIdx.y;
    const int lane = threadIdx.x;
    const int c0   = lane * CPL;
    const int r0   = band * RB;

    const float* __restrict__ Xp = X + (size_t)n * (IND * IND) + c0;
    const float* __restrict__ Yp = Y + (size_t)n * (IND * IND) + c0;

#define LOADROW(DX, DY, R) {                                                  \
    const float* _px = Xp + (size_t)(R) * IND;                                \
    const float* _py = Yp + (size_t)(R) * IND;                                \
    f32x2 _a = *(const f32x2*)_px;                                            \
    f32x2 _b = *(const f32x2*)(_px + 2);                                      \
    f32x2 _c = *(const f32x2*)(_px + 4);                                      \
    f32x2 _d = *(const f32x2*)_py;                                            \
    f32x2 _e = *(const f32x2*)(_py + 2);                                      \
    f32x2 _f = *(const f32x2*)(_py + 4);                                      \
    DX[0]=_a.x; DX[1]=_a.y; DX[2]=_b.x; DX[3]=_b.y; DX[4]=_c.x; DX[5]=_c.y;   \
    DY[0]=_d.x; DY[1]=_d.y; DY[2]=_e.x; DY[3]=_e.y; DY[4]=_f.x; DY[5]=_f.y; }

    // ---- prologue: rows r0..r0+5 -> sums; prefetch rows r0+6, r0+7 ----
    float rx[6][CPL], ry[6][CPL];            // transient (freed after accumulate)
#pragma unroll
    for (int k = 0; k < 6; ++k) LOADROW(rx[k], ry[k], r0 + k)

    float pax[CPL], pay[CPL], pbx[CPL], pby[CPL];   // new-row pipeline (2-deep)
    float oax[CPL], oay[CPL];                       // old-row pipeline (1-deep)
    LOADROW(pax, pay, r0 + 6)
    LOADROW(pbx, pby, r0 + 7)

    float sx[CPL]  = {}, sy[CPL]  = {};
    float sxx[CPL] = {}, syy[CPL] = {}, sxy[CPL] = {};
#pragma unroll
    for (int k = 0; k < 6; ++k)
#pragma unroll
        for (int c = 0; c < CPL; ++c) {
            float x = rx[k][c], y = ry[k][c];
            sx[c] += x;  sy[c] += y;
            sxx[c] = fmaf(x, x, sxx[c]);
            syy[c] = fmaf(y, y, syy[c]);
            sxy[c] = fmaf(x, y, sxy[c]);
        }
#pragma unroll
    for (int c = 0; c < CPL; ++c) { oax[c] = rx[0][c]; oay[c] = ry[0][c]; }

    const float m   = MX[n];
    const float c1  = (0.01f * m) * (0.01f * m);
    const float c2  = (0.03f * m) * (0.03f * m);
    const float k1  = 2401.0f * c1;      // 49^2 * C1
    const float k2  = 2401.0f * c2;
    const float cn  = 49.0f / 48.0f;
    const float cn2 = 2.0f * cn;

#define HSUM(S, O) {                                                          \
    float _n0 = __shfl_down(S[0], 1), _n1 = __shfl_down(S[1], 1);             \
    float _n2 = __shfl_down(S[2], 1), _n3 = __shfl_down(S[3], 1);             \
    float _n4 = __shfl_down(S[4], 1), _n5 = __shfl_down(S[5], 1);             \
    float _t  = ((S[0]+S[1]) + (S[2]+S[3])) + (S[4]+S[5]);                    \
    O[0] = _t   + _n0;                                                        \
    O[1] = O[0] - S[0] + _n1;                                                 \
    O[2] = O[1] - S[1] + _n2;                                                 \
    O[3] = O[2] - S[2] + _n3;                                                 \
    O[4] = O[3] - S[3] + _n4;                                                 \
    O[5] = O[4] - S[4] + _n5; }

    float partial = 0.f;

    // step i: sums enter holding rows r0+i..r0+i+5
#pragma unroll
    for (int i = 0; i < RB; ++i) {
        // 1. add new row r0+i+6 -> sums hold the full 7-row window
#pragma unroll
        for (int c = 0; c < CPL; ++c) {
            float nx = pax[c], ny = pay[c];
            sx[c] += nx;  sy[c] += ny;
            sxx[c] = fmaf(nx, nx, sxx[c]);
            syy[c] = fmaf(ny, ny, syy[c]);
            sxy[c] = fmaf(nx, ny, sxy[c]);
        }

        // 2. horizontal 7-tap sums (capture into t's)
        float t1[CPL], t2[CPL], t3[CPL], t4[CPL], t5[CPL];
        HSUM(sx,  t1) HSUM(sy,  t2) HSUM(sxx, t3) HSUM(syy, t4) HSUM(sxy, t5)

        // 3. subtract old row r0+i; rotate pipelines; issue next loads
#pragma unroll
        for (int c = 0; c < CPL; ++c) {
            float ox = oax[c], oy = oay[c];
            sx[c] -= ox;  sy[c] -= oy;
            sxx[c] = fmaf(-ox, ox, sxx[c]);
            syy[c] = fmaf(-oy, oy, syy[c]);
            sxy[c] = fmaf(-ox, oy, sxy[c]);
            pax[c] = pbx[c];  pay[c] = pby[c];
        }
        {
            int nr = r0 + 8 + i;  if (nr > IND - 1) nr = IND - 1;  // tail prefetch, never consumed
            LOADROW(pbx, pby, nr)
            int orr = r0 + 1 + i;                                  // always <= r0+7 <= 383
            LOADROW(oax, oay, orr)
        }

        // 4. SSIM formula for output row r0+i (scaled by 49^4; q-invariant)
        if (lane < 63) {
#pragma unroll
            for (int c = 0; c < CPL; ++c) {
                float pxy = t1[c] * t2[c];
                float ss  = fmaf(t1[c], t1[c], t2[c] * t2[c]);
                float A1  = fmaf(2.f, pxy, k1);
                float B1  = ss + k1;
                float A2  = fmaf(cn2, fmaf(49.f, t5[c], -pxy), k2);
                float B2  = fmaf(cn, fmaf(49.f, t3[c] + t4[c], -ss), k2);
                partial += __fdividef(A1 * A2, B1 * B2);
            }
        }
    }
#undef HSUM
#undef LOADROW

    // ---- wave reduction (deterministic) ----
#pragma unroll
    for (int off = 32; off; off >>= 1) partial += __shfl_down(partial, off);
    if (lane == 0) blocksum[(size_t)n * BANDS + band] = partial;
}

__global__ __launch_bounds__(256)
void ssim_reduce(const float* __restrict__ blocksum, float* __restrict__ out,
                 int nblocks, float inv_npix)
{
    const int tid = threadIdx.x;
    float s = 0.f;
    for (int i = tid; i < nblocks; i += 256) s += blocksum[i];
#pragma unroll
    for (int off = 32; off; off >>= 1) s += __shfl_down(s, off);
    __shared__ float ws[4];
    if ((tid & 63) == 0) ws[tid >> 6] = s;
    __syncthreads();
    if (tid == 0) out[0] = -(ws[0] + ws[1] + ws[2] + ws[3]) * inv_npix;
}

extern "C" void kernel_launch(void* const* d_in, const int* in_sizes, int n_in,
                              void* d_out, int out_size, void* d_ws, size_t ws_size,
                              hipStream_t stream)
{
    const float* X  = (const float*)d_in[0];
    const float* Y  = (const float*)d_in[1];
    // d_in[2] = norm (unused by reference), d_in[4] = w (ones/49, baked in)
    const float* MX = (const float*)d_in[3];

    const int N       = in_sizes[3];             // 64
    const int nblocks = N * BANDS;               // 3456

    float* bs = (float*)d_ws;

    dim3 grid(BANDS, N);
    ssim_band<<<grid, 64, 0, stream>>>(X, Y, MX, bs);

    const float inv_npix = 1.0f / ((float)N * OUTD * OUTD);
    ssim_reduce<<<1, 256, 0, stream>>>(bs, (float*)d_out, nblocks, inv_npix);
}

// Round 7
// 35.350 us; speedup vs baseline: 1.3094x; 1.3094x over previous
//
#include <hip/hip_runtime.h>

// SSIM loss, N=64 images, 1 ch, 384x384 f32, 7x7 box, VALID -> 378x378. out = -mean(S).
//
// R7 = R5 structure (register row-history, CPL=6, depth-1 shuffles) with:
//  - RB 14 -> 9: 42 bands x 64 imgs = 2688 one-wave blocks = 2.63 waves/SIMD
//    (R5 was grid-capped at 1.69; R6 proved re-loading history from cache puts
//    VMEM on the critical path, so the 84-VGPR raw history stays).
//  - History slots statically rotated via (i+6)%7 / i%7 under full unroll
//    (RB=9 constexpr): no runtime indexing -> no scratch.
//  - B2 needs only the 7-window sum of (sxx+syy): merged into ONE HSUM of
//    u = sxx+syy -> 4 HSUMs/row instead of 5 (-6 shuffles, -12 VALU per row).
//  - launch_bounds(64,3): VGPR cap 170 so 2.63 waves/SIMD are resident.

constexpr int IND   = 384;
constexpr int OUTD  = 378;
constexpr int RB    = 9;             // output rows per band
constexpr int BANDS = OUTD / RB;     // 42
constexpr int CPL   = 6;             // cols per lane (64*6 = 384 = full width)

using f32x2 = __attribute__((ext_vector_type(2))) float;

__global__ __launch_bounds__(64, 3)
void ssim_band(const float* __restrict__ X, const float* __restrict__ Y,
               const float* __restrict__ MX, float* __restrict__ blocksum)
{
    const int band = blockIdx.x;
    const int n    = blockIdx.y;
    const int lane = threadIdx.x;
    const int c0   = lane * CPL;
    const int r0   = band * RB;      // input rows r0..r0+14, all <= 383

    const float* __restrict__ Xp = X + (size_t)n * (IND * IND) + c0;
    const float* __restrict__ Yp = Y + (size_t)n * (IND * IND) + c0;

#define LOADROW(DX, DY, R) {                                                  \
    const float* _px = Xp + (size_t)(R) * IND;                                \
    const float* _py = Yp + (size_t)(R) * IND;                                \
    f32x2 _a = *(const f32x2*)_px;                                            \
    f32x2 _b = *(const f32x2*)(_px + 2);                                      \
    f32x2 _c = *(const f32x2*)(_px + 4);                                      \
    f32x2 _d = *(const f32x2*)_py;                                            \
    f32x2 _e = *(const f32x2*)(_py + 2);                                      \
    f32x2 _f = *(const f32x2*)(_py + 4);                                      \
    DX[0]=_a.x; DX[1]=_a.y; DX[2]=_b.x; DX[3]=_b.y; DX[4]=_c.x; DX[5]=_c.y;   \
    DY[0]=_d.x; DY[1]=_d.y; DY[2]=_e.x; DY[3]=_e.y; DY[4]=_f.x; DY[5]=_f.y; }

    // ---- prologue: rows r0..r0+5 straight into history slots 0..5 ----
    float hx[7][CPL], hy[7][CPL];
#pragma unroll
    for (int k = 0; k < 6; ++k) LOADROW(hx[k], hy[k], r0 + k)

    float pax[CPL], pay[CPL], pbx[CPL], pby[CPL];   // 2-deep new-row pipeline
    LOADROW(pax, pay, r0 + 6)
    LOADROW(pbx, pby, r0 + 7)

    float sx[CPL]  = {}, sy[CPL]  = {};
    float sxx[CPL] = {}, syy[CPL] = {}, sxy[CPL] = {};
#pragma unroll
    for (int k = 0; k < 6; ++k)
#pragma unroll
        for (int c = 0; c < CPL; ++c) {
            float x = hx[k][c], y = hy[k][c];
            sx[c] += x;  sy[c] += y;
            sxx[c] = fmaf(x, x, sxx[c]);
            syy[c] = fmaf(y, y, syy[c]);
            sxy[c] = fmaf(x, y, sxy[c]);
        }

    const float m   = MX[n];
    const float c1  = (0.01f * m) * (0.01f * m);
    const float c2  = (0.03f * m) * (0.03f * m);
    const float k1  = 2401.0f * c1;      // 49^2 * C1
    const float k2  = 2401.0f * c2;
    const float cn  = 49.0f / 48.0f;
    const float cn2 = 2.0f * cn;

#define HSUM(S, O) {                                                          \
    float _n0 = __shfl_down(S[0], 1), _n1 = __shfl_down(S[1], 1);             \
    float _n2 = __shfl_down(S[2], 1), _n3 = __shfl_down(S[3], 1);             \
    float _n4 = __shfl_down(S[4], 1), _n5 = __shfl_down(S[5], 1);             \
    float _t  = ((S[0]+S[1]) + (S[2]+S[3])) + (S[4]+S[5]);                    \
    O[0] = _t   + _n0;                                                        \
    O[1] = O[0] - S[0] + _n1;                                                 \
    O[2] = O[1] - S[1] + _n2;                                                 \
    O[3] = O[2] - S[2] + _n3;                                                 \
    O[4] = O[3] - S[3] + _n4;                                                 \
    O[5] = O[4] - S[4] + _n5; }

    float partial = 0.f;

    // step i: sums enter with rows [r0+i .. r0+i+5]; history holds them too.
    // write slot (i+6)%7 (freed at step i-1), subtract slot i%7.
#pragma unroll
    for (int i = 0; i < RB; ++i) {
        const int ws = (i + 6) % 7;   // constant under full unroll
        const int os = i % 7;

        // 1. add new row r0+i+6; record it in history
#pragma unroll
        for (int c = 0; c < CPL; ++c) {
            float nx = pax[c], ny = pay[c];
            sx[c] += nx;  sy[c] += ny;
            sxx[c] = fmaf(nx, nx, sxx[c]);
            syy[c] = fmaf(ny, ny, syy[c]);
            sxy[c] = fmaf(nx, ny, sxy[c]);
            hx[ws][c] = nx;  hy[ws][c] = ny;
        }

        // 2. horizontal 7-tap sums: t1, t2, t5, and merged t34 = H(sxx+syy)
        float t1[CPL], t2[CPL], t5[CPL], u[CPL], t34[CPL];
        HSUM(sx,  t1) HSUM(sy,  t2) HSUM(sxy, t5)
#pragma unroll
        for (int c = 0; c < CPL; ++c) u[c] = sxx[c] + syy[c];
        HSUM(u, t34)

        // 3. SSIM formula (scaled by 49^4; q-invariant) for output row r0+i
        if (lane < 63) {
#pragma unroll
            for (int c = 0; c < CPL; ++c) {
                float pxy = t1[c] * t2[c];
                float ss  = fmaf(t1[c], t1[c], t2[c] * t2[c]);
                float A1  = fmaf(2.f, pxy, k1);
                float B1  = ss + k1;
                float A2  = fmaf(cn2, fmaf(49.f, t5[c], -pxy), k2);
                float B2  = fmaf(cn, fmaf(49.f, t34[c], -ss), k2);
                partial += __fdividef(A1 * A2, B1 * B2);
            }
        }

        // 4. subtract old row r0+i; rotate pipeline; prefetch 2 ahead
#pragma unroll
        for (int c = 0; c < CPL; ++c) {
            float ox = hx[os][c], oy = hy[os][c];
            sx[c] -= ox;  sy[c] -= oy;
            sxx[c] = fmaf(-ox, ox, sxx[c]);
            syy[c] = fmaf(-oy, oy, syy[c]);
            sxy[c] = fmaf(-ox, oy, sxy[c]);
            pax[c] = pbx[c];  pay[c] = pby[c];
        }
        {
            int nr = r0 + 8 + i;  if (nr > IND - 1) nr = IND - 1;  // tail prefetch only
            LOADROW(pbx, pby, nr)
        }
    }
#undef HSUM
#undef LOADROW

    // ---- wave reduction (deterministic) ----
#pragma unroll
    for (int off = 32; off; off >>= 1) partial += __shfl_down(partial, off);
    if (lane == 0) blocksum[(size_t)n * BANDS + band] = partial;
}

__global__ __launch_bounds__(256)
void ssim_reduce(const float* __restrict__ blocksum, float* __restrict__ out,
                 int nblocks, float inv_npix)
{
    const int tid = threadIdx.x;
    float s = 0.f;
    for (int i = tid; i < nblocks; i += 256) s += blocksum[i];
#pragma unroll
    for (int off = 32; off; off >>= 1) s += __shfl_down(s, off);
    __shared__ float ws[4];
    if ((tid & 63) == 0) ws[tid >> 6] = s;
    __syncthreads();
    if (tid == 0) out[0] = -(ws[0] + ws[1] + ws[2] + ws[3]) * inv_npix;
}

extern "C" void kernel_launch(void* const* d_in, const int* in_sizes, int n_in,
                              void* d_out, int out_size, void* d_ws, size_t ws_size,
                              hipStream_t stream)
{
    const float* X  = (const float*)d_in[0];
    const float* Y  = (const float*)d_in[1];
    // d_in[2] = norm (unused by reference), d_in[4] = w (ones/49, baked in)
    const float* MX = (const float*)d_in[3];

    const int N       = in_sizes[3];             // 64
    const int nblocks = N * BANDS;               // 2688

    float* bs = (float*)d_ws;

    dim3 grid(BANDS, N);
    ssim_band<<<grid, 64, 0, stream>>>(X, Y, MX, bs);

    const float inv_npix = 1.0f / ((float)N * OUTD * OUTD);
    ssim_reduce<<<1, 256, 0, stream>>>(bs, (float*)d_out, nblocks, inv_npix);
}

// Round 8
// 28.453 us; speedup vs baseline: 1.6268x; 1.2424x over previous
//
#include <hip/hip_runtime.h>

// SSIM loss, N=64 images, 1 ch, 384x384 f32, 7x7 box, VALID -> 378x378. out = -mean(S).
//
// R8 = R5 (best so far, 30.2us) + two changes:
//  1. #pragma unroll 1 on the outer kk loop: R5 fully unrolled 14 steps x ~600
//     insts ~= 60 KB of straight-line code >> 32 KB I$, so every wave streams
//     instruction misses with only ~1.7 waves/SIMD to hide them (VALUBusy 24%).
//     Rolling kk keeps a 7-step (~16 KB) body I$-resident, executed twice.
//  2. t34 merge: B2 only needs the 7-window sum of (sxx+syy) -> 4 HSUMs/row
//     instead of 5 (-6 shuffles, -12 VALU per row). Mathematically identical.
// Everything else is R5 verbatim: lane owns cols 6l..6l+5 (64*6=384, no column
// clamping), 7-deep raw register history statically indexed by the unrolled
// 7-step inner loop, 2-deep new-row prefetch, depth-1 shuffles only,
// two-kernel deterministic reduction.

constexpr int IND   = 384;
constexpr int OUTD  = 378;
constexpr int RB    = 14;            // output rows per band
constexpr int BANDS = OUTD / RB;     // 27
constexpr int CPL   = 6;             // cols per lane

using f32x2 = __attribute__((ext_vector_type(2))) float;

__global__ __launch_bounds__(64, 2)
void ssim_band(const float* __restrict__ X, const float* __restrict__ Y,
               const float* __restrict__ MX, float* __restrict__ blocksum)
{
    const int band = blockIdx.x;
    const int n    = blockIdx.y;
    const int lane = threadIdx.x;
    const int c0   = lane * CPL;
    const int r0   = band * RB;      // input rows r0..r0+19, all <= 383

    const float* __restrict__ Xp = X + (size_t)n * (IND * IND) + c0;
    const float* __restrict__ Yp = Y + (size_t)n * (IND * IND) + c0;

    float hx[7][CPL], hy[7][CPL];                  // raw 7-row history
    float sx[CPL]  = {}, sy[CPL]  = {};
    float sxx[CPL] = {}, syy[CPL] = {}, sxy[CPL] = {};

#define LOADROW(DX, DY, R) {                                                  \
    const float* _px = Xp + (size_t)(R) * IND;                                \
    const float* _py = Yp + (size_t)(R) * IND;                                \
    f32x2 _a = *(const f32x2*)_px;                                            \
    f32x2 _b = *(const f32x2*)(_px + 2);                                      \
    f32x2 _c = *(const f32x2*)(_px + 4);                                      \
    f32x2 _d = *(const f32x2*)_py;                                            \
    f32x2 _e = *(const f32x2*)(_py + 2);                                      \
    f32x2 _f = *(const f32x2*)(_py + 4);                                      \
    DX[0]=_a.x; DX[1]=_a.y; DX[2]=_b.x; DX[3]=_b.y; DX[4]=_c.x; DX[5]=_c.y;   \
    DY[0]=_d.x; DY[1]=_d.y; DY[2]=_e.x; DY[3]=_e.y; DY[4]=_f.x; DY[5]=_f.y; }

    // ---- prologue: rows r0..r0+6 into history, prefetch r0+7, r0+8 ----
#pragma unroll
    for (int k = 0; k < 7; ++k) LOADROW(hx[k], hy[k], r0 + k)

    float pax[CPL], pay[CPL], pbx[CPL], pby[CPL];
    LOADROW(pax, pay, r0 + 7)
    LOADROW(pbx, pby, r0 + 8)

#pragma unroll
    for (int k = 0; k < 7; ++k)
#pragma unroll
        for (int c = 0; c < CPL; ++c) {
            float x = hx[k][c], y = hy[k][c];
            sx[c] += x;  sy[c] += y;
            sxx[c] = fmaf(x, x, sxx[c]);
            syy[c] = fmaf(y, y, syy[c]);
            sxy[c] = fmaf(x, y, sxy[c]);
        }

    const float m   = MX[n];
    const float c1  = (0.01f * m) * (0.01f * m);
    const float c2  = (0.03f * m) * (0.03f * m);
    const float k1  = 2401.0f * c1;      // 49^2 * C1
    const float k2  = 2401.0f * c2;
    const float cn  = 49.0f / 48.0f;
    const float cn2 = 2.0f * cn;

    // horizontal sliding sum: O[i] = sum over window cols (6l+i .. 6l+i+6)
#define HSUM(S, O) {                                                          \
    float _n0 = __shfl_down(S[0], 1), _n1 = __shfl_down(S[1], 1);             \
    float _n2 = __shfl_down(S[2], 1), _n3 = __shfl_down(S[3], 1);             \
    float _n4 = __shfl_down(S[4], 1), _n5 = __shfl_down(S[5], 1);             \
    float _t  = ((S[0]+S[1]) + (S[2]+S[3])) + (S[4]+S[5]);                    \
    O[0] = _t   + _n0;                                                        \
    O[1] = O[0] - S[0] + _n1;                                                 \
    O[2] = O[1] - S[1] + _n2;                                                 \
    O[3] = O[2] - S[2] + _n3;                                                 \
    O[4] = O[3] - S[3] + _n4;                                                 \
    O[5] = O[4] - S[4] + _n5; }

    float partial = 0.f;

#pragma unroll 1                       // keep the 7-step body I$-resident
    for (int kk = 0; kk < RB / 7; ++kk) {
#pragma unroll
        for (int i = 0; i < 7; ++i) {
            // ---- horizontal sums + formula for output row r0 + 7*kk + i ----
            // sums currently hold rows [r0+7kk+i .. r0+7kk+i+6]
            float t1[CPL], t2[CPL], t34[CPL], t5[CPL], u[CPL];
            HSUM(sx,  t1) HSUM(sy,  t2) HSUM(sxy, t5)
#pragma unroll
            for (int c = 0; c < CPL; ++c) u[c] = sxx[c] + syy[c];
            HSUM(u, t34)

            if (lane < 63) {
#pragma unroll
                for (int c = 0; c < CPL; ++c) {
                    float pxy = t1[c] * t2[c];
                    float ss  = fmaf(t1[c], t1[c], t2[c] * t2[c]);
                    float A1  = fmaf(2.f, pxy, k1);
                    float B1  = ss + k1;
                    float A2  = fmaf(cn2, fmaf(49.f, t5[c], -pxy), k2);
                    float B2  = fmaf(cn, fmaf(49.f, t34[c], -ss), k2);
                    partial += __fdividef(A1 * A2, B1 * B2);
                }
            }

            // ---- slide: -row(r0+7kk+i) +row(r0+7kk+i+7); refill pipeline ----
#pragma unroll
            for (int c = 0; c < CPL; ++c) {
                float nx = pax[c], ny = pay[c];
                float ox = hx[i][c], oy = hy[i][c];
                sx[c] += nx - ox;
                sy[c] += ny - oy;
                sxx[c] = fmaf(nx, nx, fmaf(-ox, ox, sxx[c]));
                syy[c] = fmaf(ny, ny, fmaf(-oy, oy, syy[c]));
                sxy[c] = fmaf(nx, ny, fmaf(-ox, oy, sxy[c]));
                hx[i][c] = nx;  hy[i][c] = ny;
                pax[c] = pbx[c]; pay[c] = pby[c];
            }
            int nr = r0 + 7 * kk + i + 9;          // 2 rows ahead
            if (nr > IND - 1) nr = IND - 1;        // tail: harmless clamped load
            LOADROW(pbx, pby, nr)
        }
    }
#undef HSUM
#undef LOADROW

    // ---- wave reduction (deterministic) ----
#pragma unroll
    for (int off = 32; off; off >>= 1) partial += __shfl_down(partial, off);
    if (lane == 0) blocksum[(size_t)n * BANDS + band] = partial;
}

__global__ __launch_bounds__(256)
void ssim_reduce(const float* __restrict__ blocksum, float* __restrict__ out,
                 int nblocks, float inv_npix)
{
    const int tid = threadIdx.x;
    float s = 0.f;
    for (int i = tid; i < nblocks; i += 256) s += blocksum[i];
#pragma unroll
    for (int off = 32; off; off >>= 1) s += __shfl_down(s, off);
    __shared__ float ws[4];
    if ((tid & 63) == 0) ws[tid >> 6] = s;
    __syncthreads();
    if (tid == 0) out[0] = -(ws[0] + ws[1] + ws[2] + ws[3]) * inv_npix;
}

extern "C" void kernel_launch(void* const* d_in, const int* in_sizes, int n_in,
                              void* d_out, int out_size, void* d_ws, size_t ws_size,
                              hipStream_t stream)
{
    const float* X  = (const float*)d_in[0];
    const float* Y  = (const float*)d_in[1];
    // d_in[2] = norm (unused by reference), d_in[4] = w (ones/49, baked in)
    const float* MX = (const float*)d_in[3];

    const int N       = in_sizes[3];             // 64
    const int nblocks = N * BANDS;               // 1728

    float* bs = (float*)d_ws;

    dim3 grid(BANDS, N);
    ssim_band<<<grid, 64, 0, stream>>>(X, Y, MX, bs);

    const float inv_npix = 1.0f / ((float)N * OUTD * OUTD);
    ssim_reduce<<<1, 256, 0, stream>>>(bs, (float*)d_out, nblocks, inv_npix);
}